// Round 16
// baseline (257.714 us; speedup 1.0000x reference)
//
#include <hip/hip_runtime.h>
#include <math.h>

#define N_NODES 50000
#define N_EDGES 800000
#define ET (N_EDGES + N_NODES)   // 850000 edges incl. self-loops
#define D 256
#define NEG_SLOPE 0.2f
#define CAP 56                                              // max degree slot capacity (P(deg>55)~1e-14)
#define XCONV_B ((N_NODES * 128 / 4 + 255) / 256)           // 6250
#define GEMM_BY ((N_NODES + 127) / 128)                     // 391
#define NCHUNK 256                                          // edge chunks for sliced scatter
#define CE ((ET + NCHUNK - 1) / NCHUNK)                     // 3321 edges per chunk
#define SLICE ((N_NODES + 7) / 8)                           // 6250 nodes per XCD slice
#define NSCAT (8 * NCHUNK)                                  // 2048 scatter blocks
#define EB ((ET + 255) / 256)                               // 3321 pack blocks
#define NB_INIT ((N_NODES + 1023) / 1024)                   // 49 cnt-zero blocks

typedef __attribute__((ext_vector_type(8))) _Float16 half8;     // MFMA A/B frag (8 f16)
typedef __attribute__((ext_vector_type(8))) unsigned short ushort8;
typedef __attribute__((ext_vector_type(4))) unsigned short us4;
typedef __attribute__((ext_vector_type(4))) float f32x4;

__device__ inline unsigned short f2h(float f) {
    union { _Float16 h; unsigned short u; } v; v.h = (_Float16)f; return v.u;
}
__device__ inline float h2f(unsigned short u) {
    union { unsigned short u; _Float16 h; } v; v.u = u; return (float)v.h;
}

// ---------------- K0: zero cnt (blocks 0..48) + pack edges to u32 (blocks 49..) ----------------
// pk[e] = (dst<<16) | src  (both < 65536). Self-loops pack arithmetically.
// Each pack block re-derives is32 locally from the SAME fixed 64 odd words
// (wave-uniform __any; identical result in every wave/block; no cross-block ordering).
__global__ __launch_bounds__(256) void pack_init(const int* __restrict__ eidx,
                                                 unsigned* __restrict__ pk,
                                                 int* __restrict__ cnt) {
    int b = blockIdx.x, t = threadIdx.x;
    if (b < NB_INIT) {             // zero cnt
        int base = b * 1024 + t * 4;
        #pragma unroll
        for (int k = 0; k < 4; ++k) {
            int i = base + k;
            if (i < N_NODES) cnt[i] = 0;
        }
        return;
    }
    b -= NB_INIT;
    // local int32-vs-int64 probe: odd 32-bit words of the first pairs are zero iff int64
    int wprobe = eidx[2 * ((t & 63) + 1) + 1];
    int is32 = __any(wprobe != 0);
    int e = b * 256 + t;
    if (e >= ET) return;
    unsigned src, dst;
    if (e >= N_EDGES) {
        unsigned n = (unsigned)(e - N_EDGES); src = n; dst = n;   // self-loop
    } else if (is32) {
        src = (unsigned)eidx[e];
        dst = (unsigned)eidx[N_EDGES + e];
    } else {
        src = (unsigned)eidx[2 * e];
        dst = (unsigned)eidx[2 * (N_EDGES + e)];
    }
    pk[e] = (dst << 16) | src;
}

// ---------------- K1: slice-privatized scatter (blocks [0,NSCAT)) || prep (rest) ----------------
// Scatter reads packed u32 edges (3.4 MB x 8 slices = 27 MB, L2/L3-resident).
__global__ __launch_bounds__(256) void scatter_prep(const unsigned* __restrict__ pk,
                                                    int* __restrict__ cnt,
                                                    unsigned short* __restrict__ psrcs,
                                                    const float* __restrict__ W1,
                                                    const float* __restrict__ W2,
                                                    const float* __restrict__ as2,
                                                    const float* __restrict__ ad2,
                                                    const float* __restrict__ x,
                                                    unsigned short* __restrict__ W1t,
                                                    unsigned short* __restrict__ W2t,
                                                    float* __restrict__ was2,
                                                    float* __restrict__ wad2,
                                                    unsigned short* __restrict__ xb) {
    int b = blockIdx.x, t = threadIdx.x;
    if (b < NSCAT) {               // slice-privatized padded-CSR scatter (L2-local atomics)
        int s = b & 7, c = b >> 3;
        int lo = s * SLICE, hi = lo + SLICE; if (hi > N_NODES) hi = N_NODES;
        int e1 = (c + 1) * CE; if (e1 > ET) e1 = ET;
        for (int e = c * CE + t; e < e1; e += 256) {
            unsigned v = pk[e];
            int dst = (int)(v >> 16);
            if (dst >= lo && dst < hi) {
                int slot = atomicAdd(&cnt[dst], 1);
                if (slot < CAP) psrcs[dst * CAP + slot] = (unsigned short)(v & 0xffffu);
            }
        }
        return;
    }
    b -= NSCAT;
    if (b < 128) {                 // W1t[n][k] = W1[k][n]
        W1t[(size_t)t * 128 + b] = f2h(W1[(size_t)b * D + t]);
    } else if (b < 384) {          // W2t[n][k] = W2[k][n]
        int k = b - 128;
        W2t[(size_t)t * D + k] = f2h(W2[(size_t)k * D + t]);
    } else if (b == 384) {         // was2/wad2 = W2 @ a_src2 / a_dst2
        float s = 0.f, d = 0.f;
        for (int j = 0; j < D; ++j) {
            float w = W2[(size_t)t * D + j];
            s += w * as2[j]; d += w * ad2[j];
        }
        was2[t] = s; wad2[t] = d;
    } else {                       // x -> f16, 4 floats/thread
        int i = (b - 385) * 256 + t;
        if (i < N_NODES * 128 / 4) {
            float4 v = *(const float4*)&x[(size_t)i * 4];
            us4 o; o.x = f2h(v.x); o.y = f2h(v.y); o.z = f2h(v.z); o.w = f2h(v.w);
            *(us4*)&xb[(size_t)i * 4] = o;
        }
    }
}

// ---------------- GEMM body (device fn): C[M x 256] = A * Bt^T, 128x128 tile ----------------
template <bool EPI, bool SCORES>
__device__ void gemm_body(int bx, int by,
                          const unsigned short* __restrict__ A,
                          const unsigned short* __restrict__ Bt,
                          void* __restrict__ Cout,
                          const float* __restrict__ bias,
                          const float* __restrict__ a_src,
                          const float* __restrict__ a_dst,
                          float* __restrict__ es,
                          float* __restrict__ ed,
                          int M, int K) {
    __shared__ __align__(16) unsigned short As[128][40];  // [row][k], pad to 40
    __shared__ __align__(16) unsigned short Bs[128][40];  // [n][k]
    int t = threadIdx.x, lane = t & 63, wid = t >> 6;
    int wm = wid >> 1, wn = wid & 1;                      // 2x2 waves, wave tile 64x64
    int row0 = by * 128, col0 = bx * 128;
    int c15 = lane & 15;
    f32x4 acc[4][4] = {};
    int ar = t >> 1, ap = t & 1;                          // A/B: 2 thr/row, 16 elems each
    for (int k0 = 0; k0 < K; k0 += 32) {
        ushort8 a0 = {0,0,0,0,0,0,0,0}, a1 = {0,0,0,0,0,0,0,0};
        if (row0 + ar < M) {
            const ushort8* p = (const ushort8*)&A[(size_t)(row0 + ar) * K + k0 + ap * 16];
            a0 = p[0]; a1 = p[1];
        }
        *(ushort8*)&As[ar][ap * 16]     = a0;
        *(ushort8*)&As[ar][ap * 16 + 8] = a1;
        const ushort8* q = (const ushort8*)&Bt[(size_t)(col0 + ar) * K + k0 + ap * 16];
        *(ushort8*)&Bs[ar][ap * 16]     = q[0];
        *(ushort8*)&Bs[ar][ap * 16 + 8] = q[1];
        __syncthreads();
        half8 af[4], bg[4];
        #pragma unroll
        for (int mi = 0; mi < 4; ++mi)
            af[mi] = *(const half8*)&As[wm * 64 + mi * 16 + c15][(lane >> 4) * 8];
        #pragma unroll
        for (int ni = 0; ni < 4; ++ni)
            bg[ni] = *(const half8*)&Bs[wn * 64 + ni * 16 + c15][(lane >> 4) * 8];
        #pragma unroll
        for (int mi = 0; mi < 4; ++mi)
            #pragma unroll
            for (int ni = 0; ni < 4; ++ni)
                acc[mi][ni] = __builtin_amdgcn_mfma_f32_16x16x32_f16(af[mi], bg[ni], acc[mi][ni], 0, 0, 0);
        __syncthreads();
    }
    float bcol[4];
    if (EPI) {
        #pragma unroll
        for (int ni = 0; ni < 4; ++ni) bcol[ni] = bias[col0 + wn * 64 + ni * 16 + c15];
    }
    #pragma unroll
    for (int mi = 0; mi < 4; ++mi) {
        int rowb = row0 + wm * 64 + mi * 16 + ((lane >> 4) << 2);
        #pragma unroll
        for (int ni = 0; ni < 4; ++ni) {
            int col = col0 + wn * 64 + ni * 16 + c15;
            #pragma unroll
            for (int r = 0; r < 4; ++r) {
                if (rowb + r >= M) continue;
                if (EPI) {
                    float v = acc[mi][ni][r] + bcol[ni];
                    v = v > 0.f ? v : __expf(v) - 1.f;
                    ((float*)Cout)[(size_t)(rowb + r) * D + col] = v;
                } else {
                    ((unsigned short*)Cout)[(size_t)(rowb + r) * D + col] = f2h(acc[mi][ni][r]);
                }
            }
        }
    }
    if (SCORES) {
        float as_[4], ad_[4];
        #pragma unroll
        for (int ni = 0; ni < 4; ++ni) {
            as_[ni] = a_src[col0 + wn * 64 + ni * 16 + c15];
            ad_[ni] = a_dst[col0 + wn * 64 + ni * 16 + c15];
        }
        int hb0 = bx * 4 + wn * 2;            // this wave's first head
        #pragma unroll
        for (int mi = 0; mi < 4; ++mi) {
            int rowb = row0 + wm * 64 + mi * 16 + ((lane >> 4) << 2);
            #pragma unroll
            for (int r = 0; r < 4; ++r) {
                float p0 = acc[mi][0][r] * as_[0] + acc[mi][1][r] * as_[1];
                float p1 = acc[mi][2][r] * as_[2] + acc[mi][3][r] * as_[3];
                float q0 = acc[mi][0][r] * ad_[0] + acc[mi][1][r] * ad_[1];
                float q1 = acc[mi][2][r] * ad_[2] + acc[mi][3][r] * ad_[3];
                #pragma unroll
                for (int msk = 1; msk < 16; msk <<= 1) {
                    p0 += __shfl_xor(p0, msk, 64);
                    p1 += __shfl_xor(p1, msk, 64);
                    q0 += __shfl_xor(q0, msk, 64);
                    q1 += __shfl_xor(q1, msk, 64);
                }
                if (c15 == 0 && rowb + r < M) {
                    es[(size_t)(rowb + r) * 8 + hb0]     = p0;
                    es[(size_t)(rowb + r) * 8 + hb0 + 1] = p1;
                    ed[(size_t)(rowb + r) * 8 + hb0]     = q0;
                    ed[(size_t)(rowb + r) * 8 + hb0 + 1] = q1;
                }
            }
        }
    }
}

// ---------------- K2: gemm1 + layer-1 scores ----------------
__global__ __launch_bounds__(256) void gemm1_scores(const unsigned short* __restrict__ xb,
                                                    const unsigned short* __restrict__ W1t,
                                                    unsigned short* __restrict__ hb,
                                                    const float* __restrict__ a_src,
                                                    const float* __restrict__ a_dst,
                                                    float* __restrict__ es,
                                                    float* __restrict__ ed) {
    gemm_body<false, true>(blockIdx.x % 2, blockIdx.x / 2, xb, W1t, hb, nullptr,
                           a_src, a_dst, es, ed, N_NODES, 128);
}

// ---------------- K6: standalone gemm2 with bias+elu epilogue ----------------
__global__ __launch_bounds__(256) void gemm2_epi(const unsigned short* __restrict__ A,
                                                 const unsigned short* __restrict__ Bt,
                                                 float* __restrict__ Cout,
                                                 const float* __restrict__ bias) {
    gemm_body<true, false>(blockIdx.x % 2, blockIdx.x / 2, A, Bt, Cout, bias,
                           nullptr, nullptr, nullptr, nullptr, N_NODES, 256);
}

// ---------------- K3: per-edge alpha (f16) via online softmax; es stays L2-hot here ----------------
__global__ __launch_bounds__(256) void softmax_alpha8(const float* __restrict__ es,
                                                      const float* __restrict__ ed,
                                                      const int* __restrict__ cnt,
                                                      const unsigned short* __restrict__ psrcs,
                                                      unsigned short* __restrict__ alpha16) {
    int n = blockIdx.x * 4 + (threadIdx.x >> 6);
    if (n >= N_NODES) return;
    int lane = threadIdx.x & 63;
    int cn = cnt[n]; if (cn > CAP) cn = CAP;
    int begin = n * CAP, end = begin + cn;
    int j  = lane >> 3;
    int hd = lane & 7;
    float edn = ed[(size_t)n * 8 + hd];
    float m = -1e30f, s = 0.f;
    for (int i = begin + j; i < end; i += 8) {
        float e = es[(size_t)psrcs[i] * 8 + hd] + edn;
        e = e > 0.f ? e : NEG_SLOPE * e;
        float nm = fmaxf(m, e);
        s = s * __expf(m - nm) + __expf(e - nm);
        m = nm;
    }
    #pragma unroll
    for (int mask = 8; mask < 64; mask <<= 1) {
        float om = __shfl_xor(m, mask, 64);
        float os = __shfl_xor(s, mask, 64);
        float nm = fmaxf(m, om);
        s = s * __expf(m - nm) + os * __expf(om - nm);
        m = nm;
    }
    float inv_s = 1.f / s;
    for (int i = begin + j; i < end; i += 8) {
        float e = es[(size_t)psrcs[i] * 8 + hd] + edn;
        e = e > 0.f ? e : NEG_SLOPE * e;
        alpha16[(size_t)i * 8 + hd] = f2h(__expf(e - m) * inv_s);
    }
}

// ---------------- K4: layer-1 gather (sequential alpha stream) + bias + elu + layer-2 scores ----------------
__global__ __launch_bounds__(256) void gather1(const unsigned short* __restrict__ h,
                                               const unsigned short* __restrict__ alpha16,
                                               const int* __restrict__ cnt,
                                               const unsigned short* __restrict__ psrcs,
                                               const float* __restrict__ bias,
                                               unsigned short* __restrict__ outh,
                                               const float* __restrict__ was2,
                                               const float* __restrict__ wad2,
                                               float* __restrict__ es2,
                                               float* __restrict__ ed2) {
    int n = blockIdx.x * 4 + (threadIdx.x >> 6);
    if (n >= N_NODES) return;
    int lane = threadIdx.x & 63;
    int cn = cnt[n]; if (cn > CAP) cn = CAP;
    int begin = n * CAP, end = begin + cn;
    int hsel = lane >> 3;
    float ax = 0.f, ay = 0.f, az = 0.f, aw = 0.f;
    int i = begin;
    for (; i + 7 < end; i += 8) {
        int ss[8]; float w[8]; us4 v[8];
        #pragma unroll
        for (int u = 0; u < 8; ++u) ss[u] = psrcs[i + u];
        #pragma unroll
        for (int u = 0; u < 8; ++u) w[u] = h2f(alpha16[(size_t)(i + u) * 8 + hsel]);
        #pragma unroll
        for (int u = 0; u < 8; ++u) v[u] = *(const us4*)&h[(size_t)ss[u] * D + lane * 4];
        #pragma unroll
        for (int u = 0; u < 8; ++u) {
            ax += h2f(v[u].x) * w[u];
            ay += h2f(v[u].y) * w[u];
            az += h2f(v[u].z) * w[u];
            aw += h2f(v[u].w) * w[u];
        }
    }
    for (; i < end; ++i) {
        int s0 = psrcs[i];
        float w0 = h2f(alpha16[(size_t)i * 8 + hsel]);
        us4 v0 = *(const us4*)&h[(size_t)s0 * D + lane * 4];
        ax += h2f(v0.x) * w0; ay += h2f(v0.y) * w0; az += h2f(v0.z) * w0; aw += h2f(v0.w) * w0;
    }
    float4 b = *(const float4*)&bias[lane * 4];
    float r0 = ax + b.x, r1 = ay + b.y, r2 = az + b.z, r3 = aw + b.w;
    r0 = r0 > 0.f ? r0 : __expf(r0) - 1.f;
    r1 = r1 > 0.f ? r1 : __expf(r1) - 1.f;
    r2 = r2 > 0.f ? r2 : __expf(r2) - 1.f;
    r3 = r3 > 0.f ? r3 : __expf(r3) - 1.f;
    us4 o; o.x = f2h(r0); o.y = f2h(r1); o.z = f2h(r2); o.w = f2h(r3);
    *(us4*)&outh[(size_t)n * D + lane * 4] = o;
    // layer-2 scores from pre-rounding f32 z
    float4 wsv = *(const float4*)&was2[lane * 4];
    float4 wdv = *(const float4*)&wad2[lane * 4];
    float ps = r0 * wsv.x + r1 * wsv.y + r2 * wsv.z + r3 * wsv.w;
    float pd = r0 * wdv.x + r1 * wdv.y + r2 * wdv.z + r3 * wdv.w;
    #pragma unroll
    for (int mask = 1; mask < 64; mask <<= 1) {
        ps += __shfl_xor(ps, mask, 64);
        pd += __shfl_xor(pd, mask, 64);
    }
    if (lane == 0) { es2[n] = ps; ed2[n] = pd; }
}

// ---------------- K5: layer-2 gather, wave-cooperative softmax (deg <= CAP <= 64) ----------------
__global__ __launch_bounds__(256) void gather2_fused(const unsigned short* __restrict__ h,
                                                     const float* __restrict__ es,
                                                     const float* __restrict__ ed,
                                                     const int* __restrict__ cnt,
                                                     const unsigned short* __restrict__ psrcs,
                                                     unsigned short* __restrict__ outh) {
    int n = blockIdx.x * 4 + (threadIdx.x >> 6);
    if (n >= N_NODES) return;
    int lane = threadIdx.x & 63;
    int begin = n * CAP;
    int cn = cnt[n]; if (cn > CAP) cn = CAP;
    float edn = ed[n];
    bool act = lane < cn;
    int sl = act ? (int)psrcs[begin + lane] : 0;
    float el = es[sl] + edn;
    el = el > 0.f ? el : NEG_SLOPE * el;
    float m = act ? el : -1e30f;
    #pragma unroll
    for (int mask = 1; mask < 64; mask <<= 1) m = fmaxf(m, __shfl_xor(m, mask, 64));
    float p = act ? __expf(el - m) : 0.f;
    float ssum = p;
    #pragma unroll
    for (int mask = 1; mask < 64; mask <<= 1) ssum += __shfl_xor(ssum, mask, 64);
    float wl = p / ssum;                   // per-lane normalized weight
    float ax = 0.f, ay = 0.f, az = 0.f, aw = 0.f;
    int j = 0;
    for (; j + 3 < cn; j += 4) {
        int s0 = __shfl(sl, j, 64),     s1 = __shfl(sl, j + 1, 64);
        int s2 = __shfl(sl, j + 2, 64), s3 = __shfl(sl, j + 3, 64);
        float w0 = __shfl(wl, j, 64),     w1 = __shfl(wl, j + 1, 64);
        float w2 = __shfl(wl, j + 2, 64), w3 = __shfl(wl, j + 3, 64);
        us4 v0 = *(const us4*)&h[(size_t)s0 * D + lane * 4];
        us4 v1 = *(const us4*)&h[(size_t)s1 * D + lane * 4];
        us4 v2 = *(const us4*)&h[(size_t)s2 * D + lane * 4];
        us4 v3 = *(const us4*)&h[(size_t)s3 * D + lane * 4];
        ax += h2f(v0.x) * w0 + h2f(v1.x) * w1 + h2f(v2.x) * w2 + h2f(v3.x) * w3;
        ay += h2f(v0.y) * w0 + h2f(v1.y) * w1 + h2f(v2.y) * w2 + h2f(v3.y) * w3;
        az += h2f(v0.z) * w0 + h2f(v1.z) * w1 + h2f(v2.z) * w2 + h2f(v3.z) * w3;
        aw += h2f(v0.w) * w0 + h2f(v1.w) * w1 + h2f(v2.w) * w2 + h2f(v3.w) * w3;
    }
    for (; j < cn; ++j) {
        int s0 = __shfl(sl, j, 64);
        float w0 = __shfl(wl, j, 64);
        us4 v0 = *(const us4*)&h[(size_t)s0 * D + lane * 4];
        ax += h2f(v0.x) * w0; ay += h2f(v0.y) * w0; az += h2f(v0.z) * w0; aw += h2f(v0.w) * w0;
    }
    us4 o; o.x = f2h(ax); o.y = f2h(ay); o.z = f2h(az); o.w = f2h(aw);
    *(us4*)&outh[(size_t)n * D + lane * 4] = o;
}

// ---------------- launch ----------------
extern "C" void kernel_launch(void* const* d_in, const int* in_sizes, int n_in,
                              void* d_out, int out_size, void* d_ws, size_t ws_size,
                              hipStream_t stream) {
    const float* x        = (const float*)d_in[0];
    const int*   eidx     = (const int*)d_in[1];
    const float* W1       = (const float*)d_in[2];
    const float* att_src1 = (const float*)d_in[3];
    const float* att_dst1 = (const float*)d_in[4];
    const float* b1       = (const float*)d_in[5];
    const float* W2       = (const float*)d_in[6];
    const float* att_src2 = (const float*)d_in[7];
    const float* att_dst2 = (const float*)d_in[8];
    const float* b2       = (const float*)d_in[9];
    float* out = (float*)d_out;

    char* ws = (char*)d_ws;
    size_t o = 0;
    auto take = [&](size_t bytes) { char* p = ws + o; o = (o + bytes + 255) & ~(size_t)255; return p; };
    unsigned short* hb    = (unsigned short*)take((size_t)N_NODES * D * 2);   // h1, later agg2
    unsigned short* zb    = (unsigned short*)take((size_t)N_NODES * D * 2);   // layer-1 output z
    unsigned short* xb    = (unsigned short*)take((size_t)N_NODES * 128 * 2);
    unsigned short* W1t   = (unsigned short*)take((size_t)D * 128 * 2);
    unsigned short* W2t   = (unsigned short*)take((size_t)D * D * 2);
    unsigned short* alpha16 = (unsigned short*)take((size_t)N_NODES * CAP * 8 * 2);  // 44.8 MB
    float* es1  = (float*)take((size_t)N_NODES * 8 * 4);
    float* ed1  = (float*)take((size_t)N_NODES * 8 * 4);
    float* es2  = (float*)take((size_t)N_NODES * 4);
    float* ed2  = (float*)take((size_t)N_NODES * 4);
    float* was2 = (float*)take(D * 4);
    float* wad2 = (float*)take(D * 4);
    unsigned*       pk    = (unsigned*)take((size_t)ET * 4);                  // 3.4 MB packed edges
    unsigned short* psrcs = (unsigned short*)take((size_t)N_NODES * CAP * 2); // 5.6 MB
    int*   cnt  = (int*)take((size_t)N_NODES * 4);

    const int NBLK = (N_NODES + 3) / 4;

    // K0: zero cnt + pack edges (local is32 probe per block)
    pack_init<<<NB_INIT + EB, 256, 0, stream>>>(eidx, pk, cnt);
    // K1: slice-privatized scatter (packed edges) || prep (both light footprints)
    scatter_prep<<<NSCAT + 385 + XCONV_B, 256, 0, stream>>>(pk, cnt, psrcs,
                                                            W1, W2, att_src2, att_dst2, x,
                                                            W1t, W2t, was2, wad2, xb);
    // K2: gemm1 (+layer-1 scores)
    gemm1_scores<<<2 * GEMM_BY, 256, 0, stream>>>(xb, W1t, hb, att_src1, att_dst1, es1, ed1);
    // K3: alpha materialization (es L2-hot, no h streaming here)
    softmax_alpha8<<<NBLK, 256, 0, stream>>>(es1, ed1, cnt, psrcs, alpha16);
    // K4: layer-1 gather (+layer-2 scores)
    gather1<<<NBLK, 256, 0, stream>>>(hb, alpha16, cnt, psrcs, b1, zb, was2, wad2, es2, ed2);
    // K5: layer-2 gather with wave-coop softmax
    gather2_fused<<<NBLK, 256, 0, stream>>>(zb, es2, ed2, cnt, psrcs, hb);
    // K6: gemm2 with bias+elu epilogue -> f32 out
    gemm2_epi<<<2 * GEMM_BY, 256, 0, stream>>>(hb, W2t, out, b2);
}

// Round 17
// 255.909 us; speedup vs baseline: 1.0071x; 1.0071x over previous
//
#include <hip/hip_runtime.h>
#include <math.h>

#define N_NODES 50000
#define N_EDGES 800000
#define ET (N_EDGES + N_NODES)   // 850000 edges incl. self-loops
#define D 256
#define NEG_SLOPE 0.2f
#define CAP 56                                              // max degree slot capacity (P(deg>55)~1e-14)
#define XCONV_B ((N_NODES * 128 / 4 + 255) / 256)           // 6250
#define GEMM_BY ((N_NODES + 127) / 128)                     // 391
#define NCHUNK 256                                          // edge chunks for sliced scatter
#define CE ((ET + NCHUNK - 1) / NCHUNK)                     // 3321 edges per chunk
#define SLICE ((N_NODES + 7) / 8)                           // 6250 nodes per XCD slice
#define NSCAT (8 * NCHUNK)                                  // 2048 scatter blocks

typedef __attribute__((ext_vector_type(8))) _Float16 half8;     // MFMA A/B frag (8 f16)
typedef __attribute__((ext_vector_type(8))) unsigned short ushort8;
typedef __attribute__((ext_vector_type(4))) unsigned short us4;
typedef __attribute__((ext_vector_type(4))) float f32x4;

__device__ inline unsigned short f2h(float f) {
    union { _Float16 h; unsigned short u; } v; v.h = (_Float16)f; return v.u;
}
__device__ inline float h2f(unsigned short u) {
    union { unsigned short u; _Float16 h; } v; v.u = u; return (float)v.h;
}

__device__ inline int edge_src(const int* eidx, int is32, int e) {
    if (e >= N_EDGES) return e - N_EDGES;
    return is32 ? eidx[e] : eidx[2 * e];
}
__device__ inline int edge_dst(const int* eidx, int is32, int e) {
    if (e >= N_EDGES) return e - N_EDGES;
    return is32 ? eidx[N_EDGES + e] : eidx[2 * (N_EDGES + e)];
}

// ---------------- K0: detect edge format (block 0) + zero cnt (blocks 1..49) ----------------
__global__ __launch_bounds__(256) void init_all(const int* __restrict__ eidx,
                                                int* __restrict__ flag,
                                                int* __restrict__ cnt) {
    int b = blockIdx.x, t = threadIdx.x;
    if (b == 0) {
        __shared__ int any32;
        if (t == 0) any32 = 0;
        __syncthreads();
        int found = 0;
        #pragma unroll
        for (int k = 0; k < 4; ++k) {
            int i = t * 4 + k;                 // i < 1024
            if (eidx[2 * i + 1] != 0) found = 1;
        }
        if (found) atomicOr(&any32, 1);        // LDS atomic
        __syncthreads();
        if (t == 0) *flag = any32;             // single writer, no pre-zero needed
    } else {
        int base = (b - 1) * 1024 + t * 4;
        #pragma unroll
        for (int k = 0; k < 4; ++k) {
            int i = base + k;
            if (i < N_NODES) cnt[i] = 0;
        }
    }
}

// ---------------- K1: slice-privatized scatter (blocks [0,NSCAT)) || prep (rest) ----------------
// Both branches are LDS-free / low-VGPR -> safe to co-schedule.
__global__ __launch_bounds__(256) void scatter_prep(const int* __restrict__ eidx,
                                                    const int* __restrict__ flag,
                                                    int* __restrict__ cnt,
                                                    unsigned short* __restrict__ psrcs,
                                                    const float* __restrict__ W1,
                                                    const float* __restrict__ W2,
                                                    const float* __restrict__ as2,
                                                    const float* __restrict__ ad2,
                                                    const float* __restrict__ x,
                                                    unsigned short* __restrict__ W1t,
                                                    unsigned short* __restrict__ W2t,
                                                    float* __restrict__ was2,
                                                    float* __restrict__ wad2,
                                                    unsigned short* __restrict__ xb) {
    int b = blockIdx.x, t = threadIdx.x;
    if (b < NSCAT) {               // slice-privatized padded-CSR scatter (L2-local atomics)
        int s = b & 7, c = b >> 3;
        int is32 = *flag;
        int lo = s * SLICE, hi = lo + SLICE; if (hi > N_NODES) hi = N_NODES;
        int e1 = (c + 1) * CE; if (e1 > ET) e1 = ET;
        for (int e = c * CE + t; e < e1; e += 256) {
            int dst = edge_dst(eidx, is32, e);
            if (dst >= lo && dst < hi) {
                int src = edge_src(eidx, is32, e);
                int slot = atomicAdd(&cnt[dst], 1);
                if (slot < CAP) psrcs[dst * CAP + slot] = (unsigned short)src;
            }
        }
        return;
    }
    b -= NSCAT;
    if (b < 128) {                 // W1t[n][k] = W1[k][n]
        W1t[(size_t)t * 128 + b] = f2h(W1[(size_t)b * D + t]);
    } else if (b < 384) {          // W2t[n][k] = W2[k][n]
        int k = b - 128;
        W2t[(size_t)t * D + k] = f2h(W2[(size_t)k * D + t]);
    } else if (b == 384) {         // was2/wad2 = W2 @ a_src2 / a_dst2
        float s = 0.f, d = 0.f;
        for (int j = 0; j < D; ++j) {
            float w = W2[(size_t)t * D + j];
            s += w * as2[j]; d += w * ad2[j];
        }
        was2[t] = s; wad2[t] = d;
    } else {                       // x -> f16, 4 floats/thread
        int i = (b - 385) * 256 + t;
        if (i < N_NODES * 128 / 4) {
            float4 v = *(const float4*)&x[(size_t)i * 4];
            us4 o; o.x = f2h(v.x); o.y = f2h(v.y); o.z = f2h(v.z); o.w = f2h(v.w);
            *(us4*)&xb[(size_t)i * 4] = o;
        }
    }
}

// ---------------- GEMM body (device fn): C[M x 256] = A * Bt^T, 128x128 tile ----------------
template <bool EPI, bool SCORES>
__device__ void gemm_body(int bx, int by,
                          const unsigned short* __restrict__ A,
                          const unsigned short* __restrict__ Bt,
                          void* __restrict__ Cout,
                          const float* __restrict__ bias,
                          const float* __restrict__ a_src,
                          const float* __restrict__ a_dst,
                          float* __restrict__ es,
                          float* __restrict__ ed,
                          int M, int K) {
    __shared__ __align__(16) unsigned short As[128][40];  // [row][k], pad to 40
    __shared__ __align__(16) unsigned short Bs[128][40];  // [n][k]
    int t = threadIdx.x, lane = t & 63, wid = t >> 6;
    int wm = wid >> 1, wn = wid & 1;                      // 2x2 waves, wave tile 64x64
    int row0 = by * 128, col0 = bx * 128;
    int c15 = lane & 15;
    f32x4 acc[4][4] = {};
    int ar = t >> 1, ap = t & 1;                          // A/B: 2 thr/row, 16 elems each
    for (int k0 = 0; k0 < K; k0 += 32) {
        ushort8 a0 = {0,0,0,0,0,0,0,0}, a1 = {0,0,0,0,0,0,0,0};
        if (row0 + ar < M) {
            const ushort8* p = (const ushort8*)&A[(size_t)(row0 + ar) * K + k0 + ap * 16];
            a0 = p[0]; a1 = p[1];
        }
        *(ushort8*)&As[ar][ap * 16]     = a0;
        *(ushort8*)&As[ar][ap * 16 + 8] = a1;
        const ushort8* q = (const ushort8*)&Bt[(size_t)(col0 + ar) * K + k0 + ap * 16];
        *(ushort8*)&Bs[ar][ap * 16]     = q[0];
        *(ushort8*)&Bs[ar][ap * 16 + 8] = q[1];
        __syncthreads();
        half8 af[4], bg[4];
        #pragma unroll
        for (int mi = 0; mi < 4; ++mi)
            af[mi] = *(const half8*)&As[wm * 64 + mi * 16 + c15][(lane >> 4) * 8];
        #pragma unroll
        for (int ni = 0; ni < 4; ++ni)
            bg[ni] = *(const half8*)&Bs[wn * 64 + ni * 16 + c15][(lane >> 4) * 8];
        #pragma unroll
        for (int mi = 0; mi < 4; ++mi)
            #pragma unroll
            for (int ni = 0; ni < 4; ++ni)
                acc[mi][ni] = __builtin_amdgcn_mfma_f32_16x16x32_f16(af[mi], bg[ni], acc[mi][ni], 0, 0, 0);
        __syncthreads();
    }
    float bcol[4];
    if (EPI) {
        #pragma unroll
        for (int ni = 0; ni < 4; ++ni) bcol[ni] = bias[col0 + wn * 64 + ni * 16 + c15];
    }
    #pragma unroll
    for (int mi = 0; mi < 4; ++mi) {
        int rowb = row0 + wm * 64 + mi * 16 + ((lane >> 4) << 2);
        #pragma unroll
        for (int ni = 0; ni < 4; ++ni) {
            int col = col0 + wn * 64 + ni * 16 + c15;
            #pragma unroll
            for (int r = 0; r < 4; ++r) {
                if (rowb + r >= M) continue;
                if (EPI) {
                    float v = acc[mi][ni][r] + bcol[ni];
                    v = v > 0.f ? v : __expf(v) - 1.f;
                    ((float*)Cout)[(size_t)(rowb + r) * D + col] = v;
                } else {
                    ((unsigned short*)Cout)[(size_t)(rowb + r) * D + col] = f2h(acc[mi][ni][r]);
                }
            }
        }
    }
    if (SCORES) {
        float as_[4], ad_[4];
        #pragma unroll
        for (int ni = 0; ni < 4; ++ni) {
            as_[ni] = a_src[col0 + wn * 64 + ni * 16 + c15];
            ad_[ni] = a_dst[col0 + wn * 64 + ni * 16 + c15];
        }
        int hb0 = bx * 4 + wn * 2;            // this wave's first head
        #pragma unroll
        for (int mi = 0; mi < 4; ++mi) {
            int rowb = row0 + wm * 64 + mi * 16 + ((lane >> 4) << 2);
            #pragma unroll
            for (int r = 0; r < 4; ++r) {
                float p0 = acc[mi][0][r] * as_[0] + acc[mi][1][r] * as_[1];
                float p1 = acc[mi][2][r] * as_[2] + acc[mi][3][r] * as_[3];
                float q0 = acc[mi][0][r] * ad_[0] + acc[mi][1][r] * ad_[1];
                float q1 = acc[mi][2][r] * ad_[2] + acc[mi][3][r] * ad_[3];
                #pragma unroll
                for (int msk = 1; msk < 16; msk <<= 1) {
                    p0 += __shfl_xor(p0, msk, 64);
                    p1 += __shfl_xor(p1, msk, 64);
                    q0 += __shfl_xor(q0, msk, 64);
                    q1 += __shfl_xor(q1, msk, 64);
                }
                if (c15 == 0 && rowb + r < M) {
                    es[(size_t)(rowb + r) * 8 + hb0]     = p0;
                    es[(size_t)(rowb + r) * 8 + hb0 + 1] = p1;
                    ed[(size_t)(rowb + r) * 8 + hb0]     = q0;
                    ed[(size_t)(rowb + r) * 8 + hb0 + 1] = q1;
                }
            }
        }
    }
}

// ---------------- K2: gemm1 + layer-1 scores ----------------
__global__ __launch_bounds__(256) void gemm1_scores(const unsigned short* __restrict__ xb,
                                                    const unsigned short* __restrict__ W1t,
                                                    unsigned short* __restrict__ hb,
                                                    const float* __restrict__ a_src,
                                                    const float* __restrict__ a_dst,
                                                    float* __restrict__ es,
                                                    float* __restrict__ ed) {
    gemm_body<false, true>(blockIdx.x % 2, blockIdx.x / 2, xb, W1t, hb, nullptr,
                           a_src, a_dst, es, ed, N_NODES, 128);
}

// ---------------- K6: standalone gemm2 with bias+elu epilogue ----------------
__global__ __launch_bounds__(256) void gemm2_epi(const unsigned short* __restrict__ A,
                                                 const unsigned short* __restrict__ Bt,
                                                 float* __restrict__ Cout,
                                                 const float* __restrict__ bias) {
    gemm_body<true, false>(blockIdx.x % 2, blockIdx.x / 2, A, Bt, Cout, bias,
                           nullptr, nullptr, nullptr, nullptr, N_NODES, 256);
}

// ---------------- K3: per-edge alpha (f16) via online softmax; es stays L2-hot here ----------------
__global__ __launch_bounds__(256) void softmax_alpha8(const float* __restrict__ es,
                                                      const float* __restrict__ ed,
                                                      const int* __restrict__ cnt,
                                                      const unsigned short* __restrict__ psrcs,
                                                      unsigned short* __restrict__ alpha16) {
    int n = blockIdx.x * 4 + (threadIdx.x >> 6);
    if (n >= N_NODES) return;
    int lane = threadIdx.x & 63;
    int cn = cnt[n]; if (cn > CAP) cn = CAP;
    int begin = n * CAP, end = begin + cn;
    int j  = lane >> 3;
    int hd = lane & 7;
    float edn = ed[(size_t)n * 8 + hd];
    float m = -1e30f, s = 0.f;
    for (int i = begin + j; i < end; i += 8) {
        float e = es[(size_t)psrcs[i] * 8 + hd] + edn;
        e = e > 0.f ? e : NEG_SLOPE * e;
        float nm = fmaxf(m, e);
        s = s * __expf(m - nm) + __expf(e - nm);
        m = nm;
    }
    #pragma unroll
    for (int mask = 8; mask < 64; mask <<= 1) {
        float om = __shfl_xor(m, mask, 64);
        float os = __shfl_xor(s, mask, 64);
        float nm = fmaxf(m, om);
        s = s * __expf(m - nm) + os * __expf(om - nm);
        m = nm;
    }
    float inv_s = 1.f / s;
    for (int i = begin + j; i < end; i += 8) {
        float e = es[(size_t)psrcs[i] * 8 + hd] + edn;
        e = e > 0.f ? e : NEG_SLOPE * e;
        alpha16[(size_t)i * 8 + hd] = f2h(__expf(e - m) * inv_s);
    }
}

// ---------------- K4: layer-1 gather (sequential alpha stream) + bias + elu + layer-2 scores ----------------
__global__ __launch_bounds__(256) void gather1(const unsigned short* __restrict__ h,
                                               const unsigned short* __restrict__ alpha16,
                                               const int* __restrict__ cnt,
                                               const unsigned short* __restrict__ psrcs,
                                               const float* __restrict__ bias,
                                               unsigned short* __restrict__ outh,
                                               const float* __restrict__ was2,
                                               const float* __restrict__ wad2,
                                               float* __restrict__ es2,
                                               float* __restrict__ ed2) {
    int n = blockIdx.x * 4 + (threadIdx.x >> 6);
    if (n >= N_NODES) return;
    int lane = threadIdx.x & 63;
    int cn = cnt[n]; if (cn > CAP) cn = CAP;
    int begin = n * CAP, end = begin + cn;
    int hsel = lane >> 3;
    float ax = 0.f, ay = 0.f, az = 0.f, aw = 0.f;
    int i = begin;
    for (; i + 7 < end; i += 8) {
        int ss[8]; float w[8]; us4 v[8];
        #pragma unroll
        for (int u = 0; u < 8; ++u) ss[u] = psrcs[i + u];
        #pragma unroll
        for (int u = 0; u < 8; ++u) w[u] = h2f(alpha16[(size_t)(i + u) * 8 + hsel]);
        #pragma unroll
        for (int u = 0; u < 8; ++u) v[u] = *(const us4*)&h[(size_t)ss[u] * D + lane * 4];
        #pragma unroll
        for (int u = 0; u < 8; ++u) {
            ax += h2f(v[u].x) * w[u];
            ay += h2f(v[u].y) * w[u];
            az += h2f(v[u].z) * w[u];
            aw += h2f(v[u].w) * w[u];
        }
    }
    for (; i < end; ++i) {
        int s0 = psrcs[i];
        float w0 = h2f(alpha16[(size_t)i * 8 + hsel]);
        us4 v0 = *(const us4*)&h[(size_t)s0 * D + lane * 4];
        ax += h2f(v0.x) * w0; ay += h2f(v0.y) * w0; az += h2f(v0.z) * w0; aw += h2f(v0.w) * w0;
    }
    float4 b = *(const float4*)&bias[lane * 4];
    float r0 = ax + b.x, r1 = ay + b.y, r2 = az + b.z, r3 = aw + b.w;
    r0 = r0 > 0.f ? r0 : __expf(r0) - 1.f;
    r1 = r1 > 0.f ? r1 : __expf(r1) - 1.f;
    r2 = r2 > 0.f ? r2 : __expf(r2) - 1.f;
    r3 = r3 > 0.f ? r3 : __expf(r3) - 1.f;
    us4 o; o.x = f2h(r0); o.y = f2h(r1); o.z = f2h(r2); o.w = f2h(r3);
    *(us4*)&outh[(size_t)n * D + lane * 4] = o;
    // layer-2 scores from pre-rounding f32 z
    float4 wsv = *(const float4*)&was2[lane * 4];
    float4 wdv = *(const float4*)&wad2[lane * 4];
    float ps = r0 * wsv.x + r1 * wsv.y + r2 * wsv.z + r3 * wsv.w;
    float pd = r0 * wdv.x + r1 * wdv.y + r2 * wdv.z + r3 * wdv.w;
    #pragma unroll
    for (int mask = 1; mask < 64; mask <<= 1) {
        ps += __shfl_xor(ps, mask, 64);
        pd += __shfl_xor(pd, mask, 64);
    }
    if (lane == 0) { es2[n] = ps; ed2[n] = pd; }
}

// ---------------- K5: layer-2 gather, wave-cooperative softmax (deg <= CAP <= 64) ----------------
__global__ __launch_bounds__(256) void gather2_fused(const unsigned short* __restrict__ h,
                                                     const float* __restrict__ es,
                                                     const float* __restrict__ ed,
                                                     const int* __restrict__ cnt,
                                                     const unsigned short* __restrict__ psrcs,
                                                     unsigned short* __restrict__ outh) {
    int n = blockIdx.x * 4 + (threadIdx.x >> 6);
    if (n >= N_NODES) return;
    int lane = threadIdx.x & 63;
    int begin = n * CAP;
    int cn = cnt[n]; if (cn > CAP) cn = CAP;
    float edn = ed[n];
    bool act = lane < cn;
    int sl = act ? (int)psrcs[begin + lane] : 0;
    float el = es[sl] + edn;
    el = el > 0.f ? el : NEG_SLOPE * el;
    float m = act ? el : -1e30f;
    #pragma unroll
    for (int mask = 1; mask < 64; mask <<= 1) m = fmaxf(m, __shfl_xor(m, mask, 64));
    float p = act ? __expf(el - m) : 0.f;
    float ssum = p;
    #pragma unroll
    for (int mask = 1; mask < 64; mask <<= 1) ssum += __shfl_xor(ssum, mask, 64);
    float wl = p / ssum;                   // per-lane normalized weight
    float ax = 0.f, ay = 0.f, az = 0.f, aw = 0.f;
    int j = 0;
    for (; j + 3 < cn; j += 4) {
        int s0 = __shfl(sl, j, 64),     s1 = __shfl(sl, j + 1, 64);
        int s2 = __shfl(sl, j + 2, 64), s3 = __shfl(sl, j + 3, 64);
        float w0 = __shfl(wl, j, 64),     w1 = __shfl(wl, j + 1, 64);
        float w2 = __shfl(wl, j + 2, 64), w3 = __shfl(wl, j + 3, 64);
        us4 v0 = *(const us4*)&h[(size_t)s0 * D + lane * 4];
        us4 v1 = *(const us4*)&h[(size_t)s1 * D + lane * 4];
        us4 v2 = *(const us4*)&h[(size_t)s2 * D + lane * 4];
        us4 v3 = *(const us4*)&h[(size_t)s3 * D + lane * 4];
        ax += h2f(v0.x) * w0 + h2f(v1.x) * w1 + h2f(v2.x) * w2 + h2f(v3.x) * w3;
        ay += h2f(v0.y) * w0 + h2f(v1.y) * w1 + h2f(v2.y) * w2 + h2f(v3.y) * w3;
        az += h2f(v0.z) * w0 + h2f(v1.z) * w1 + h2f(v2.z) * w2 + h2f(v3.z) * w3;
        aw += h2f(v0.w) * w0 + h2f(v1.w) * w1 + h2f(v2.w) * w2 + h2f(v3.w) * w3;
    }
    for (; j < cn; ++j) {
        int s0 = __shfl(sl, j, 64);
        float w0 = __shfl(wl, j, 64);
        us4 v0 = *(const us4*)&h[(size_t)s0 * D + lane * 4];
        ax += h2f(v0.x) * w0; ay += h2f(v0.y) * w0; az += h2f(v0.z) * w0; aw += h2f(v0.w) * w0;
    }
    us4 o; o.x = f2h(ax); o.y = f2h(ay); o.z = f2h(az); o.w = f2h(aw);
    *(us4*)&outh[(size_t)n * D + lane * 4] = o;
}

// ---------------- launch ----------------
extern "C" void kernel_launch(void* const* d_in, const int* in_sizes, int n_in,
                              void* d_out, int out_size, void* d_ws, size_t ws_size,
                              hipStream_t stream) {
    const float* x        = (const float*)d_in[0];
    const int*   eidx     = (const int*)d_in[1];
    const float* W1       = (const float*)d_in[2];
    const float* att_src1 = (const float*)d_in[3];
    const float* att_dst1 = (const float*)d_in[4];
    const float* b1       = (const float*)d_in[5];
    const float* W2       = (const float*)d_in[6];
    const float* att_src2 = (const float*)d_in[7];
    const float* att_dst2 = (const float*)d_in[8];
    const float* b2       = (const float*)d_in[9];
    float* out = (float*)d_out;

    char* ws = (char*)d_ws;
    size_t o = 0;
    auto take = [&](size_t bytes) { char* p = ws + o; o = (o + bytes + 255) & ~(size_t)255; return p; };
    unsigned short* hb    = (unsigned short*)take((size_t)N_NODES * D * 2);   // h1, later agg2
    unsigned short* zb    = (unsigned short*)take((size_t)N_NODES * D * 2);   // layer-1 output z
    unsigned short* xb    = (unsigned short*)take((size_t)N_NODES * 128 * 2);
    unsigned short* W1t   = (unsigned short*)take((size_t)D * 128 * 2);
    unsigned short* W2t   = (unsigned short*)take((size_t)D * D * 2);
    unsigned short* alpha16 = (unsigned short*)take((size_t)N_NODES * CAP * 8 * 2);  // 44.8 MB
    float* es1  = (float*)take((size_t)N_NODES * 8 * 4);
    float* ed1  = (float*)take((size_t)N_NODES * 8 * 4);
    float* es2  = (float*)take((size_t)N_NODES * 4);
    float* ed2  = (float*)take((size_t)N_NODES * 4);
    float* was2 = (float*)take(D * 4);
    float* wad2 = (float*)take(D * 4);
    unsigned short* psrcs = (unsigned short*)take((size_t)N_NODES * CAP * 2); // 5.6 MB
    int*   cnt  = (int*)take((size_t)N_NODES * 4);
    int*   flag = (int*)take(256);

    const int NBLK = (N_NODES + 3) / 4;
    const int NB_INIT = (N_NODES + 1023) / 1024;   // 49

    // K0: detect fmt + zero cnt
    init_all<<<1 + NB_INIT, 256, 0, stream>>>(eidx, flag, cnt);
    // K1: slice-privatized scatter || prep (both light footprints)
    scatter_prep<<<NSCAT + 385 + XCONV_B, 256, 0, stream>>>(eidx, flag, cnt, psrcs,
                                                            W1, W2, att_src2, att_dst2, x,
                                                            W1t, W2t, was2, wad2, xb);
    // K2: gemm1 (+layer-1 scores)
    gemm1_scores<<<2 * GEMM_BY, 256, 0, stream>>>(xb, W1t, hb, att_src1, att_dst1, es1, ed1);
    // K3: alpha materialization (es L2-hot, no h streaming here)
    softmax_alpha8<<<NBLK, 256, 0, stream>>>(es1, ed1, cnt, psrcs, alpha16);
    // K4: layer-1 gather (+layer-2 scores)
    gather1<<<NBLK, 256, 0, stream>>>(hb, alpha16, cnt, psrcs, b1, zb, was2, wad2, es2, ed2);
    // K5: layer-2 gather with wave-coop softmax
    gather2_fused<<<NBLK, 256, 0, stream>>>(zb, es2, ed2, cnt, psrcs, hb);
    // K6: gemm2 with bias+elu epilogue -> f32 out
    gemm2_epi<<<2 * GEMM_BY, 256, 0, stream>>>(hb, W2t, out, b2);
}